// Round 6
// baseline (4306.156 us; speedup 1.0000x reference)
//
#include <hip/hip_runtime.h>

#define ROWS 32768      // B*T
#define D 512
#define NCODES 8192
#define NSPLIT 4
#define CODES_PER_SPLIT (NCODES / NSPLIT)   // 2048
#define BM 32           // rows per block (8 per wave)
#define BN 512          // codes per tile
#define BKK 16          // k per stage
#define KC 384          // OpenBLAS sgemm kc panel split (verified exact, round 4)

// numpy pairwise f32 sum of squares of a 512-float row (verified exact).
__device__ __forceinline__ float np_sumsq_512(const float* __restrict__ p) {
    float blk[4];
#pragma unroll
    for (int b = 0; b < 4; ++b) {
        const float* q = p + b * 128;
        float r[8];
#pragma unroll
        for (int j = 0; j < 8; ++j) r[j] = __fmul_rn(q[j], q[j]);
#pragma unroll
        for (int i = 1; i < 16; ++i)
#pragma unroll
            for (int j = 0; j < 8; ++j)
                r[j] = __fadd_rn(r[j], __fmul_rn(q[i * 8 + j], q[i * 8 + j]));
        blk[b] = __fadd_rn(__fadd_rn(__fadd_rn(r[0], r[1]), __fadd_rn(r[2], r[3])),
                           __fadd_rn(__fadd_rn(r[4], r[5]), __fadd_rn(r[6], r[7])));
    }
    return __fadd_rn(__fadd_rn(blk[0], blk[1]), __fadd_rn(blk[2], blk[3]));
}

// ---------------- kernel 1: row sums of squares ----------------
__global__ void k_rowsums(const float* __restrict__ zE, const float* __restrict__ cb,
                          float* __restrict__ sq, float* __restrict__ e2) {
    int row = blockIdx.x * 64 + threadIdx.x;
    if (row < ROWS) {
        sq[row] = np_sumsq_512(zE + (size_t)row * D);
    } else {
        e2[row - ROWS] = np_sumsq_512(cb + (size_t)(row - ROWS) * D);
    }
}

// ---------------- kernel 2: distance GEMM + fused partial argmin ----------------
// 4 waves/block; wave owns 8 rows x 2048 codes; lane owns 8 rows x 8 codes.
// A-fragment LDS reads are wave-uniform (broadcast, ~free BW); B-reads are the
// only real LDS traffic: 0.5 B per lane-FMA -> FMA-bound.
// Numerics per (row,code): m = fl(chain(k=0..383) + chain(k=384..511)),
// sequential ascending-k FMA; dist = fl(fl(s-2m)+e2). Bit-exact (round 4).
__global__ __launch_bounds__(256, 2)
void k_argmin(const float* __restrict__ zE, const float* __restrict__ cb,
              const float* __restrict__ sq, const float* __restrict__ e2,
              uint2* __restrict__ part) {
    __shared__ float As[BKK][BM];       // [k][row]  2 KiB
    __shared__ float Bs[BKK][BN];       // [k][code] 32 KiB

    const int cs      = blockIdx.x;
    const int rowBase = blockIdx.y * BM;
    const int tid     = threadIdx.x;
    const int lane    = tid & 63;
    const int w8      = (tid >> 6) * 8;      // wave's row offset within block
    const int sr8     = tid >> 1;            // B-staging code 0..127
    const int sk8     = (tid & 1) * 8;       // B-staging k-half

    float srow[8];
#pragma unroll
    for (int i = 0; i < 8; ++i) srow[i] = sq[rowBase + w8 + i];

    float bv[8];
    int   bi[8];
#pragma unroll
    for (int i = 0; i < 8; ++i) { bv[i] = INFINITY; bi[i] = 0; }

    for (int ct = 0; ct < CODES_PER_SPLIT / BN; ++ct) {   // 4 code tiles
        const int codeBase = cs * CODES_PER_SPLIT + ct * BN;
        float acc[8][8], m1[8][8];
#pragma unroll
        for (int i = 0; i < 8; ++i)
#pragma unroll
            for (int j = 0; j < 8; ++j) { acc[i][j] = 0.0f; m1[i][j] = 0.0f; }

        for (int ks = 0; ks < D / BKK; ++ks) {            // 32 K stages, k ascending
            __syncthreads();
            if (tid < 128) {                              // stage A (2 KiB)
                int row = tid >> 2;
                int sk  = (tid & 3) * 4;
                float4 va = *(const float4*)(zE + (size_t)(rowBase + row) * D + ks * BKK + sk);
                As[sk + 0][row] = va.x;  As[sk + 1][row] = va.y;
                As[sk + 2][row] = va.z;  As[sk + 3][row] = va.w;
            }
#pragma unroll
            for (int q = 0; q < 4; ++q) {                 // stage B (32 KiB)
                int c = sr8 + 128 * q;
                const float* g = cb + (size_t)(codeBase + c) * D + ks * BKK + sk8;
                float4 v0 = *(const float4*)g;
                float4 v1 = *(const float4*)(g + 4);
                Bs[sk8 + 0][c] = v0.x;  Bs[sk8 + 1][c] = v0.y;
                Bs[sk8 + 2][c] = v0.z;  Bs[sk8 + 3][c] = v0.w;
                Bs[sk8 + 4][c] = v1.x;  Bs[sk8 + 5][c] = v1.y;
                Bs[sk8 + 6][c] = v1.z;  Bs[sk8 + 7][c] = v1.w;
            }
            __syncthreads();
#pragma unroll
            for (int k = 0; k < BKK; ++k) {
                float4 a0 = *(const float4*)&As[k][w8];        // wave-uniform: broadcast
                float4 a1 = *(const float4*)&As[k][w8 + 4];
                float4 b0 = *(const float4*)&Bs[k][lane * 4];        // all 32 banks
                float4 b1 = *(const float4*)&Bs[k][256 + lane * 4];
                float av[8] = {a0.x, a0.y, a0.z, a0.w, a1.x, a1.y, a1.z, a1.w};
                float bw[8] = {b0.x, b0.y, b0.z, b0.w, b1.x, b1.y, b1.z, b1.w};
#pragma unroll
                for (int i = 0; i < 8; ++i)
#pragma unroll
                    for (int j = 0; j < 8; ++j)
                        acc[i][j] = __builtin_fmaf(av[i], bw[j], acc[i][j]);
            }
            if (ks == KC / BKK - 1) {                     // close panel 1 (k=0..383)
#pragma unroll
                for (int i = 0; i < 8; ++i)
#pragma unroll
                    for (int j = 0; j < 8; ++j) { m1[i][j] = acc[i][j]; acc[i][j] = 0.0f; }
            }
        }

        // dist = fl(fl(s - 2*fl(S1+S2)) + e2); within-lane ascending code order
#pragma unroll
        for (int j = 0; j < 8; ++j) {
            int c = codeBase + ((j < 4) ? (lane * 4 + j) : (256 + lane * 4 + (j - 4)));
            float ec = e2[c];
#pragma unroll
            for (int i = 0; i < 8; ++i) {
                float m = __fadd_rn(m1[i][j], acc[i][j]);
                float d = __fadd_rn(__fsub_rn(srow[i], __fmul_rn(2.0f, m)), ec);
                if (d < bv[i]) { bv[i] = d; bi[i] = c; }
            }
        }
    }

    // wave-level lexicographic (val, idx) argmin reduce; lanes hold disjoint codes
#pragma unroll
    for (int i = 0; i < 8; ++i) {
        float v = bv[i];
        int   x = bi[i];
#pragma unroll
        for (int off = 32; off; off >>= 1) {
            float v2 = __shfl_xor(v, off);
            int   x2 = __shfl_xor(x, off);
            if (v2 < v || (v2 == v && x2 < x)) { v = v2; x = x2; }
        }
        if (lane == 0)
            part[(size_t)(rowBase + w8 + i) * NSPLIT + cs] =
                make_uint2(__float_as_uint(v), (unsigned)x);
    }
}

// ---------------- kernel 3: reduce partials -> ids (f32 output) ----------------
__global__ void k_pick(const uint2* __restrict__ part, int* __restrict__ ids,
                       float* __restrict__ outIds) {
    int rr = blockIdx.x * blockDim.x + threadIdx.x;
    if (rr >= ROWS) return;
    float bvv = __uint_as_float(part[(size_t)rr * NSPLIT].x);
    int   bii = (int)part[(size_t)rr * NSPLIT].y;
    for (int cs2 = 1; cs2 < NSPLIT; ++cs2) {
        float v = __uint_as_float(part[(size_t)rr * NSPLIT + cs2].x);
        int   x = (int)part[(size_t)rr * NSPLIT + cs2].y;
        if (v < bvv || (v == bvv && x < bii)) { bvv = v; bii = x; }
    }
    bii = bii < 0 ? 0 : (bii > NCODES - 1 ? NCODES - 1 : bii);
    ids[rr] = bii;
    outIds[rr] = (float)bii;
}

// ---------------- kernel 4: gather z_q_st (f32) + loss partials ----------------
__global__ void k_gather(const float* __restrict__ zE, const float* __restrict__ cb,
                         const int* __restrict__ ids, float* __restrict__ outZ,
                         double* __restrict__ lossPart) {
    const int tid = threadIdx.x;
    double acc = 0.0;
#pragma unroll
    for (int it = 0; it < 4; ++it) {
        int chunk = blockIdx.x * 256 + tid + it * 1048576;   // float4 chunk id
        int row   = chunk >> 7;
        int koff  = (chunk & 127) << 2;
        int id    = ids[row];
        id = id < 0 ? 0 : (id > NCODES - 1 ? NCODES - 1 : id);
        float4 ze = *(const float4*)(zE + ((size_t)row << 9) + koff);
        float4 zq = *(const float4*)(cb + ((size_t)id << 9) + koff);
        float d0 = __fsub_rn(zq.x, ze.x);
        float d1 = __fsub_rn(zq.y, ze.y);
        float d2 = __fsub_rn(zq.z, ze.z);
        float d3 = __fsub_rn(zq.w, ze.w);
        float4 v;
        v.x = __fadd_rn(ze.x, d0);
        v.y = __fadd_rn(ze.y, d1);
        v.z = __fadd_rn(ze.z, d2);
        v.w = __fadd_rn(ze.w, d3);
        *reinterpret_cast<float4*>(outZ + ((size_t)chunk << 2)) = v;
        acc += (double)d0 * d0 + (double)d1 * d1 + (double)d2 * d2 + (double)d3 * d3;
    }
    for (int off = 32; off; off >>= 1) acc += __shfl_down(acc, off);
    __shared__ double sred[4];
    if ((tid & 63) == 0) sred[tid >> 6] = acc;
    __syncthreads();
    if (tid == 0) lossPart[blockIdx.x] = (sred[0] + sred[1]) + (sred[2] + sred[3]);
}

// ---------------- kernel 5: final loss (f32 output) ----------------
__global__ void k_loss(const double* __restrict__ lossPart, float* __restrict__ outLoss) {
    const int tid = threadIdx.x;
    double acc = 0.0;
    for (int i = tid; i < 4096; i += 256) acc += lossPart[i];
    for (int off = 32; off; off >>= 1) acc += __shfl_down(acc, off);
    __shared__ double sred[4];
    if ((tid & 63) == 0) sred[tid >> 6] = acc;
    __syncthreads();
    if (tid == 0) {
        double mean = ((sred[0] + sred[1]) + (sred[2] + sred[3])) / 16777216.0;
        float cl = (float)mean;
        *outLoss = __fadd_rn(cl, __fmul_rn(0.25f, cl));
    }
}

extern "C" void kernel_launch(void* const* d_in, const int* in_sizes, int n_in,
                              void* d_out, int out_size, void* d_ws, size_t ws_size,
                              hipStream_t stream) {
    (void)in_sizes; (void)n_in; (void)out_size; (void)ws_size;
    const float* zE = (const float*)d_in[0];
    const float* cb = (const float*)d_in[1];
    float* out = (float*)d_out;                    // f32 outputs, concatenated
    char* ws = (char*)d_ws;

    float*  sq       = (float*)(ws + 0);         // 32768 f32
    float*  e2       = (float*)(ws + 131072);    // 8192  f32
    int*    ids      = (int*)(ws + 163840);      // 32768 i32
    uint2*  part     = (uint2*)(ws + 294912);    // 32768*4 uint2 = 1 MiB
    double* lossPart = (double*)(ws + 1343488);  // 4096  f64

    k_rowsums<<<(ROWS + NCODES) / 64, 64, 0, stream>>>(zE, cb, sq, e2);
    dim3 g2(NSPLIT, ROWS / BM);
    k_argmin<<<g2, 256, 0, stream>>>(zE, cb, sq, e2, part);
    k_pick<<<ROWS / 256, 256, 0, stream>>>(part, ids, out + 16777216);
    k_gather<<<4096, 256, 0, stream>>>(zE, cb, ids, out, lossPart);
    k_loss<<<1, 256, 0, stream>>>(lossPart, out + 16777216 + 32768);
}

// Round 7
// 4032.442 us; speedup vs baseline: 1.0679x; 1.0679x over previous
//
#include <hip/hip_runtime.h>

#define ROWS 32768      // B*T
#define D 512
#define NCODES 8192
#define NSPLIT 4
#define CODES_PER_SPLIT (NCODES / NSPLIT)   // 2048
#define BM 64           // rows per block (8 per wave, 8 waves)
#define BN 256          // codes per tile
#define BKK 16          // k per stage
#define KC 384          // OpenBLAS sgemm kc panel split (verified exact, round 4)

// numpy pairwise f32 sum of squares of a 512-float row (verified exact).
__device__ __forceinline__ float np_sumsq_512(const float* __restrict__ p) {
    float blk[4];
#pragma unroll
    for (int b = 0; b < 4; ++b) {
        const float* q = p + b * 128;
        float r[8];
#pragma unroll
        for (int j = 0; j < 8; ++j) r[j] = __fmul_rn(q[j], q[j]);
#pragma unroll
        for (int i = 1; i < 16; ++i)
#pragma unroll
            for (int j = 0; j < 8; ++j)
                r[j] = __fadd_rn(r[j], __fmul_rn(q[i * 8 + j], q[i * 8 + j]));
        blk[b] = __fadd_rn(__fadd_rn(__fadd_rn(r[0], r[1]), __fadd_rn(r[2], r[3])),
                           __fadd_rn(__fadd_rn(r[4], r[5]), __fadd_rn(r[6], r[7])));
    }
    return __fadd_rn(__fadd_rn(blk[0], blk[1]), __fadd_rn(blk[2], blk[3]));
}

// ---------------- kernel 1: row sums of squares ----------------
__global__ void k_rowsums(const float* __restrict__ zE, const float* __restrict__ cb,
                          float* __restrict__ sq, float* __restrict__ e2) {
    int row = blockIdx.x * 64 + threadIdx.x;
    if (row < ROWS) {
        sq[row] = np_sumsq_512(zE + (size_t)row * D);
    } else {
        e2[row - ROWS] = np_sumsq_512(cb + (size_t)(row - ROWS) * D);
    }
}

// ---------------- kernel 2: distance GEMM + fused partial argmin ----------------
// 512 thr = 8 waves; wave owns 8 rows; lane owns 8 rows x 4 codes (per tile).
// A-reads are wave-uniform b128 broadcasts (~free LDS BW); B is 1 distinct b128
// per lane-k -> 0.5 B/lane-FMA -> VALU(FMA)-bound, not LDS-bound.
// acc+m1 = 64 VGPRs (vs 128 in round 6 which spilled to scratch).
// Numerics per (row,code): m = fl(chain(k=0..383) + chain(k=384..511)),
// sequential ascending-k FMA; dist = fl(fl(s-2m)+e2). Bit-exact (rounds 4-6).
__global__ __launch_bounds__(512, 2)
void k_argmin(const float* __restrict__ zE, const float* __restrict__ cb,
              const float* __restrict__ sq, const float* __restrict__ e2,
              uint2* __restrict__ part) {
    __shared__ float As[BKK][BM];       // [k][row]   4 KiB
    __shared__ float Bs[BKK][BN];       // [k][code] 16 KiB

    const int cs      = blockIdx.x;
    const int rowBase = blockIdx.y * BM;
    const int tid     = threadIdx.x;
    const int lane    = tid & 63;
    const int w8      = (tid >> 6) * 8;      // wave's row offset within block
    const int sc      = tid >> 1;            // B-staging code 0..255
    const int sk8     = (tid & 1) * 8;       // B-staging k-half

    float srow[8];
#pragma unroll
    for (int i = 0; i < 8; ++i) srow[i] = sq[rowBase + w8 + i];

    float bv[8];
    int   bi[8];
#pragma unroll
    for (int i = 0; i < 8; ++i) { bv[i] = INFINITY; bi[i] = 0; }

    for (int ct = 0; ct < CODES_PER_SPLIT / BN; ++ct) {   // 8 code tiles
        const int codeBase = cs * CODES_PER_SPLIT + ct * BN;
        float acc[8][4], m1[8][4];
#pragma unroll
        for (int i = 0; i < 8; ++i)
#pragma unroll
            for (int j = 0; j < 4; ++j) { acc[i][j] = 0.0f; m1[i][j] = 0.0f; }

        for (int ks = 0; ks < D / BKK; ++ks) {            // 32 K stages, k ascending
            __syncthreads();
            if (tid < 256) {                              // stage A (4 KiB)
                int row = tid >> 2;
                int sk  = (tid & 3) * 4;
                float4 va = *(const float4*)(zE + (size_t)(rowBase + row) * D + ks * BKK + sk);
                As[sk + 0][row] = va.x;  As[sk + 1][row] = va.y;
                As[sk + 2][row] = va.z;  As[sk + 3][row] = va.w;
            }
            {                                             // stage B (16 KiB)
                const float* g = cb + (size_t)(codeBase + sc) * D + ks * BKK + sk8;
                float4 v0 = *(const float4*)g;
                float4 v1 = *(const float4*)(g + 4);
                Bs[sk8 + 0][sc] = v0.x;  Bs[sk8 + 1][sc] = v0.y;
                Bs[sk8 + 2][sc] = v0.z;  Bs[sk8 + 3][sc] = v0.w;
                Bs[sk8 + 4][sc] = v1.x;  Bs[sk8 + 5][sc] = v1.y;
                Bs[sk8 + 6][sc] = v1.z;  Bs[sk8 + 7][sc] = v1.w;
            }
            __syncthreads();
#pragma unroll
            for (int k = 0; k < BKK; ++k) {
                float4 a0 = *(const float4*)&As[k][w8];        // wave-uniform broadcast
                float4 a1 = *(const float4*)&As[k][w8 + 4];
                float4 b0 = *(const float4*)&Bs[k][lane * 4];  // all 32 banks
                float av[8] = {a0.x, a0.y, a0.z, a0.w, a1.x, a1.y, a1.z, a1.w};
                float bw[4] = {b0.x, b0.y, b0.z, b0.w};
#pragma unroll
                for (int i = 0; i < 8; ++i)
#pragma unroll
                    for (int j = 0; j < 4; ++j)
                        acc[i][j] = __builtin_fmaf(av[i], bw[j], acc[i][j]);
            }
            if (ks == KC / BKK - 1) {                     // close panel 1 (k=0..383)
#pragma unroll
                for (int i = 0; i < 8; ++i)
#pragma unroll
                    for (int j = 0; j < 4; ++j) { m1[i][j] = acc[i][j]; acc[i][j] = 0.0f; }
            }
        }

        // dist = fl(fl(s - 2*fl(S1+S2)) + e2); per-lane ascending code order
#pragma unroll
        for (int j = 0; j < 4; ++j) {
            int c = codeBase + lane * 4 + j;
            float ec = e2[c];
#pragma unroll
            for (int i = 0; i < 8; ++i) {
                float m = __fadd_rn(m1[i][j], acc[i][j]);
                float d = __fadd_rn(__fsub_rn(srow[i], __fmul_rn(2.0f, m)), ec);
                if (d < bv[i]) { bv[i] = d; bi[i] = c; }
            }
        }
    }

    // wave-level lexicographic (val, idx) argmin reduce; lanes hold disjoint codes
#pragma unroll
    for (int i = 0; i < 8; ++i) {
        float v = bv[i];
        int   x = bi[i];
#pragma unroll
        for (int off = 32; off; off >>= 1) {
            float v2 = __shfl_xor(v, off);
            int   x2 = __shfl_xor(x, off);
            if (v2 < v || (v2 == v && x2 < x)) { v = v2; x = x2; }
        }
        if (lane == 0)
            part[(size_t)(rowBase + w8 + i) * NSPLIT + cs] =
                make_uint2(__float_as_uint(v), (unsigned)x);
    }
}

// ---------------- kernel 3: reduce partials -> ids (f32 output) ----------------
__global__ void k_pick(const uint2* __restrict__ part, int* __restrict__ ids,
                       float* __restrict__ outIds) {
    int rr = blockIdx.x * blockDim.x + threadIdx.x;
    if (rr >= ROWS) return;
    float bvv = __uint_as_float(part[(size_t)rr * NSPLIT].x);
    int   bii = (int)part[(size_t)rr * NSPLIT].y;
    for (int cs2 = 1; cs2 < NSPLIT; ++cs2) {
        float v = __uint_as_float(part[(size_t)rr * NSPLIT + cs2].x);
        int   x = (int)part[(size_t)rr * NSPLIT + cs2].y;
        if (v < bvv || (v == bvv && x < bii)) { bvv = v; bii = x; }
    }
    bii = bii < 0 ? 0 : (bii > NCODES - 1 ? NCODES - 1 : bii);
    ids[rr] = bii;
    outIds[rr] = (float)bii;
}

// ---------------- kernel 4: gather z_q_st (f32) + loss partials ----------------
__global__ void k_gather(const float* __restrict__ zE, const float* __restrict__ cb,
                         const int* __restrict__ ids, float* __restrict__ outZ,
                         double* __restrict__ lossPart) {
    const int tid = threadIdx.x;
    double acc = 0.0;
#pragma unroll
    for (int it = 0; it < 4; ++it) {
        int chunk = blockIdx.x * 256 + tid + it * 1048576;   // float4 chunk id
        int row   = chunk >> 7;
        int koff  = (chunk & 127) << 2;
        int id    = ids[row];
        id = id < 0 ? 0 : (id > NCODES - 1 ? NCODES - 1 : id);
        float4 ze = *(const float4*)(zE + ((size_t)row << 9) + koff);
        float4 zq = *(const float4*)(cb + ((size_t)id << 9) + koff);
        float d0 = __fsub_rn(zq.x, ze.x);
        float d1 = __fsub_rn(zq.y, ze.y);
        float d2 = __fsub_rn(zq.z, ze.z);
        float d3 = __fsub_rn(zq.w, ze.w);
        float4 v;
        v.x = __fadd_rn(ze.x, d0);
        v.y = __fadd_rn(ze.y, d1);
        v.z = __fadd_rn(ze.z, d2);
        v.w = __fadd_rn(ze.w, d3);
        *reinterpret_cast<float4*>(outZ + ((size_t)chunk << 2)) = v;
        acc += (double)d0 * d0 + (double)d1 * d1 + (double)d2 * d2 + (double)d3 * d3;
    }
    for (int off = 32; off; off >>= 1) acc += __shfl_down(acc, off);
    __shared__ double sred[4];
    if ((tid & 63) == 0) sred[tid >> 6] = acc;
    __syncthreads();
    if (tid == 0) lossPart[blockIdx.x] = (sred[0] + sred[1]) + (sred[2] + sred[3]);
}

// ---------------- kernel 5: final loss (f32 output) ----------------
__global__ void k_loss(const double* __restrict__ lossPart, float* __restrict__ outLoss) {
    const int tid = threadIdx.x;
    double acc = 0.0;
    for (int i = tid; i < 4096; i += 256) acc += lossPart[i];
    for (int off = 32; off; off >>= 1) acc += __shfl_down(acc, off);
    __shared__ double sred[4];
    if ((tid & 63) == 0) sred[tid >> 6] = acc;
    __syncthreads();
    if (tid == 0) {
        double mean = ((sred[0] + sred[1]) + (sred[2] + sred[3])) / 16777216.0;
        float cl = (float)mean;
        *outLoss = __fadd_rn(cl, __fmul_rn(0.25f, cl));
    }
}

extern "C" void kernel_launch(void* const* d_in, const int* in_sizes, int n_in,
                              void* d_out, int out_size, void* d_ws, size_t ws_size,
                              hipStream_t stream) {
    (void)in_sizes; (void)n_in; (void)out_size; (void)ws_size;
    const float* zE = (const float*)d_in[0];
    const float* cb = (const float*)d_in[1];
    float* out = (float*)d_out;                    // f32 outputs, concatenated
    char* ws = (char*)d_ws;

    float*  sq       = (float*)(ws + 0);         // 32768 f32
    float*  e2       = (float*)(ws + 131072);    // 8192  f32
    int*    ids      = (int*)(ws + 163840);      // 32768 i32
    uint2*  part     = (uint2*)(ws + 294912);    // 32768*4 uint2 = 1 MiB
    double* lossPart = (double*)(ws + 1343488);  // 4096  f64

    k_rowsums<<<(ROWS + NCODES) / 64, 64, 0, stream>>>(zE, cb, sq, e2);
    dim3 g2(NSPLIT, ROWS / BM);
    k_argmin<<<g2, 512, 0, stream>>>(zE, cb, sq, e2, part);
    k_pick<<<ROWS / 256, 256, 0, stream>>>(part, ids, out + 16777216);
    k_gather<<<4096, 256, 0, stream>>>(zE, cb, ids, out, lossPart);
    k_loss<<<1, 256, 0, stream>>>(lossPart, out + 16777216 + 32768);
}